// Round 1
// baseline (1195.352 us; speedup 1.0000x reference)
//
#include <hip/hip_runtime.h>

#define B_BATCH 8
#define SEQ 4096
#define D_MODEL 1024
#define D_STATE 64
#define EPS 1e-6f

__device__ __forceinline__ float sigmoidf(float v) {
    return 1.0f / (1.0f + __expf(-v));
}

// ---------------------------------------------------------------------------
// Kernel 0: apply sigmoids, transpose B_w to [D][N]
// ---------------------------------------------------------------------------
__global__ __launch_bounds__(256) void prep_kernel(
    const float* __restrict__ A_raw, const float* __restrict__ B_w,
    const float* __restrict__ C_w, const float* __restrict__ gamma,
    float* __restrict__ As, float* __restrict__ Bt, float* __restrict__ Cs,
    float* __restrict__ gs) {
    int i = blockIdx.x * 256 + threadIdx.x;   // 0 .. D*N-1
    int d = i >> 6;
    int n = i & 63;
    As[i] = sigmoidf(A_raw[i]);               // [D][N]
    Cs[i] = sigmoidf(C_w[i]);                 // [D][N]
    Bt[i] = sigmoidf(B_w[n * D_MODEL + d]);   // Bt[d][n] = sigmoid(B_w[n][d])
    if (n == 0) gs[d] = sigmoidf(gamma[d]);
}

// ---------------------------------------------------------------------------
// Kernel 1: U[row][n] = sum_d x[row][d] * Bt[d][n]   (row = b*SEQ + t)
// 256 threads = 16x16, each thread 4 rows x 4 n; block tile 64 rows x 64 n.
// ---------------------------------------------------------------------------
__device__ __forceinline__ void fma4(float av, const float4 bv, float* acc) {
    acc[0] = fmaf(av, bv.x, acc[0]);
    acc[1] = fmaf(av, bv.y, acc[1]);
    acc[2] = fmaf(av, bv.z, acc[2]);
    acc[3] = fmaf(av, bv.w, acc[3]);
}

__global__ __launch_bounds__(256) void u_gemm_kernel(
    const float* __restrict__ x, const float* __restrict__ Bt,
    float* __restrict__ U) {
    __shared__ float xs[64 * 68];   // [row][d] pad 68 for bank spread
    __shared__ float Bs[64 * 64];   // [d][n]
    const int tid = threadIdx.x;
    const int row0 = blockIdx.x * 64;
    const int tr = tid >> 4;        // 0..15 row-group
    const int tc = tid & 15;        // 0..15 n-group
    float acc[4][4] = {};

    for (int d0 = 0; d0 < D_MODEL; d0 += 64) {
        // stage x tile [64 rows][64 d]
#pragma unroll
        for (int i = 0; i < 4; ++i) {
            int f4 = i * 1024 + tid * 4;
            int r = f4 >> 6, c = f4 & 63;
            float4 v = *(const float4*)&x[(size_t)(row0 + r) * D_MODEL + d0 + c];
            *(float4*)&xs[r * 68 + c] = v;
        }
        // stage B tile [64 d][64 n] (contiguous in Bt)
#pragma unroll
        for (int i = 0; i < 4; ++i) {
            int f4 = i * 1024 + tid * 4;
            *(float4*)&Bs[f4] = *(const float4*)&Bt[d0 * 64 + f4];
        }
        __syncthreads();
#pragma unroll
        for (int dd = 0; dd < 64; dd += 4) {
            float4 b0 = *(const float4*)&Bs[(dd + 0) * 64 + tc * 4];
            float4 b1 = *(const float4*)&Bs[(dd + 1) * 64 + tc * 4];
            float4 b2 = *(const float4*)&Bs[(dd + 2) * 64 + tc * 4];
            float4 b3 = *(const float4*)&Bs[(dd + 3) * 64 + tc * 4];
#pragma unroll
            for (int i = 0; i < 4; ++i) {
                float4 a = *(const float4*)&xs[(tr * 4 + i) * 68 + dd];
                fma4(a.x, b0, acc[i]);
                fma4(a.y, b1, acc[i]);
                fma4(a.z, b2, acc[i]);
                fma4(a.w, b3, acc[i]);
            }
        }
        __syncthreads();
    }
#pragma unroll
    for (int i = 0; i < 4; ++i) {
        float4 v = make_float4(acc[i][0], acc[i][1], acc[i][2], acc[i][3]);
        *(float4*)&U[(size_t)(row0 + tr * 4 + i) * 64 + tc * 4] = v;
    }
}

// ---------------------------------------------------------------------------
// Kernel 2: sequential scan. Block = (b, 32 d-values). 8 lanes per d, 8 n/lane.
// Emits UNNORMALIZED y[b,t,d] into yraw (= d_out region 0) and h_final.
// ---------------------------------------------------------------------------
__global__ __launch_bounds__(256) void scan_kernel(
    const float* __restrict__ x, const float* __restrict__ U,
    const float* __restrict__ As, const float* __restrict__ Cs,
    float* __restrict__ yraw, float* __restrict__ hout) {
    __shared__ float Ulds[64 * 64];   // [tt][n]
    __shared__ float xlds[64 * 32];   // [tt][dd]
    __shared__ float ylds[64 * 32];   // [tt][dd]
    const int tid = threadIdx.x;
    const int b = blockIdx.x >> 5;
    const int d0 = (blockIdx.x & 31) * 32;
    const int g = tid >> 3;           // 0..31  -> d = d0+g
    const int l = tid & 7;            // 0..7   -> n = l*8 .. l*8+7
    const int d = d0 + g;

    float h[8], a[8], c[8];
    {
        float4 a0 = *(const float4*)&As[d * 64 + l * 8];
        float4 a1 = *(const float4*)&As[d * 64 + l * 8 + 4];
        a[0] = a0.x; a[1] = a0.y; a[2] = a0.z; a[3] = a0.w;
        a[4] = a1.x; a[5] = a1.y; a[6] = a1.z; a[7] = a1.w;
        float4 c0 = *(const float4*)&Cs[d * 64 + l * 8];
        float4 c1 = *(const float4*)&Cs[d * 64 + l * 8 + 4];
        c[0] = c0.x; c[1] = c0.y; c[2] = c0.z; c[3] = c0.w;
        c[4] = c1.x; c[5] = c1.y; c[6] = c1.z; c[7] = c1.w;
    }
#pragma unroll
    for (int j = 0; j < 8; ++j) h[j] = 0.0f;

    const size_t xbase = (size_t)b * SEQ * D_MODEL;
    const size_t ubase = (size_t)b * SEQ * 64;

    for (int t0 = 0; t0 < SEQ; t0 += 64) {
        // stage U chunk: 64 steps x 64 n (contiguous 16 KB)
#pragma unroll
        for (int i = 0; i < 4; ++i) {
            int f4 = i * 1024 + tid * 4;
            *(float4*)&Ulds[f4] = *(const float4*)&U[ubase + (size_t)t0 * 64 + f4];
        }
        // stage x chunk: 64 steps x 32 d
#pragma unroll
        for (int i = 0; i < 2; ++i) {
            int f4 = i * 1024 + tid * 4;
            int tt = f4 >> 5, dd = f4 & 31;
            *(float4*)&xlds[f4] =
                *(const float4*)&x[xbase + (size_t)(t0 + tt) * D_MODEL + d0 + dd];
        }
        __syncthreads();

#pragma unroll 4
        for (int tt = 0; tt < 64; ++tt) {
            float4 u0 = *(const float4*)&Ulds[tt * 64 + l * 8];
            float4 u1 = *(const float4*)&Ulds[tt * 64 + l * 8 + 4];
            float xt = xlds[tt * 32 + g];
            float uu[8] = {u0.x, u0.y, u0.z, u0.w, u1.x, u1.y, u1.z, u1.w};
            float y = 0.0f;
#pragma unroll
            for (int j = 0; j < 8; ++j) {
                h[j] = __builtin_amdgcn_fmed3f(fmaf(h[j], a[j], uu[j] * xt),
                                               0.0f, 1.0f);
                y = fmaf(h[j], c[j], y);
            }
            // reduce y across the 8 lanes of this d-group
            y += __shfl_xor(y, 1);
            y += __shfl_xor(y, 2);
            y += __shfl_xor(y, 4);
            if (l == 0) ylds[tt * 32 + g] = y;
        }
        __syncthreads();

        // flush y chunk, coalesced
#pragma unroll
        for (int i = 0; i < 2; ++i) {
            int f4 = i * 1024 + tid * 4;
            int tt = f4 >> 5, dd = f4 & 31;
            *(float4*)&yraw[xbase + (size_t)(t0 + tt) * D_MODEL + d0 + dd] =
                *(const float4*)&ylds[f4];
        }
        // next iteration's staging is fenced by the post-stage __syncthreads()
    }

    // h_final [B][D][N]
    float4 h0 = make_float4(h[0], h[1], h[2], h[3]);
    float4 h1 = make_float4(h[4], h[5], h[6], h[7]);
    size_t hoff = ((size_t)b * D_MODEL + d) * 64 + l * 8;
    *(float4*)&hout[hoff] = h0;
    *(float4*)&hout[hoff + 4] = h1;
}

// ---------------------------------------------------------------------------
// Kernel 3: in-place normalize: out = clip(g*y/(sum_d y + eps) + x, 0, 1)
// One block per (b,t) row.
// ---------------------------------------------------------------------------
__global__ __launch_bounds__(256) void norm_kernel(
    const float* __restrict__ x, const float* __restrict__ gs,
    float* __restrict__ y) {
    __shared__ float red[4];
    const int tid = threadIdx.x;
    const size_t base = (size_t)blockIdx.x * D_MODEL;

    float4 yv = *(const float4*)&y[base + tid * 4];
    float s = yv.x + yv.y + yv.z + yv.w;
#pragma unroll
    for (int off = 1; off < 64; off <<= 1) s += __shfl_xor(s, off);
    if ((tid & 63) == 0) red[tid >> 6] = s;
    __syncthreads();
    float tot = red[0] + red[1] + red[2] + red[3];
    float inv = 1.0f / (tot + EPS);

    float4 xv = *(const float4*)&x[base + tid * 4];
    float4 gv = *(const float4*)&gs[tid * 4];
    float4 o;
    o.x = __builtin_amdgcn_fmed3f(fmaf(gv.x * yv.x, inv, xv.x), 0.0f, 1.0f);
    o.y = __builtin_amdgcn_fmed3f(fmaf(gv.y * yv.y, inv, xv.y), 0.0f, 1.0f);
    o.z = __builtin_amdgcn_fmed3f(fmaf(gv.z * yv.z, inv, xv.z), 0.0f, 1.0f);
    o.w = __builtin_amdgcn_fmed3f(fmaf(gv.w * yv.w, inv, xv.w), 0.0f, 1.0f);
    *(float4*)&y[base + tid * 4] = o;
}

// ---------------------------------------------------------------------------
extern "C" void kernel_launch(void* const* d_in, const int* in_sizes, int n_in,
                              void* d_out, int out_size, void* d_ws,
                              size_t ws_size, hipStream_t stream) {
    const float* x     = (const float*)d_in[0];
    const float* A_raw = (const float*)d_in[1];
    const float* B_w   = (const float*)d_in[2];
    const float* C_w   = (const float*)d_in[3];
    const float* gamma = (const float*)d_in[4];

    float* out  = (float*)d_out;
    float* yout = out;                                      // [B,S,D]
    float* hout = out + (size_t)B_BATCH * SEQ * D_MODEL;    // [B,D,N]

    float* ws = (float*)d_ws;
    float* As = ws;                  // 65536
    float* Bt = ws + 65536;          // 65536
    float* Cs = ws + 131072;         // 65536
    float* gs = ws + 196608;         // 1024
    float* U  = ws + 197632;         // B*SEQ*64 = 2097152

    prep_kernel<<<256, 256, 0, stream>>>(A_raw, B_w, C_w, gamma, As, Bt, Cs, gs);
    u_gemm_kernel<<<(B_BATCH * SEQ) / 64, 256, 0, stream>>>(x, Bt, U);
    scan_kernel<<<B_BATCH * (D_MODEL / 32), 256, 0, stream>>>(x, U, As, Cs,
                                                              yout, hout);
    norm_kernel<<<B_BATCH * SEQ, 256, 0, stream>>>(x, gs, yout);
}

// Round 2
// 587.055 us; speedup vs baseline: 2.0362x; 2.0362x over previous
//
#include <hip/hip_runtime.h>

#define B_BATCH 8
#define SEQ 4096
#define D_MODEL 1024
#define D_STATE 64
#define EPS 1e-6f

#define T_CHUNK 512   // time steps per scan block (8 chunks)
#define WARM 64       // redundant warm-up steps; A<=0.7311 => 0.7311^64 ~ 2e-9
#define ROUND 32      // steps staged in LDS per round

__device__ __forceinline__ float sigmoidf(float v) {
    return 1.0f / (1.0f + __expf(-v));
}

// ---------------------------------------------------------------------------
// Kernel 0: apply sigmoids, transpose B_w to [D][N]
// ---------------------------------------------------------------------------
__global__ __launch_bounds__(256) void prep_kernel(
    const float* __restrict__ A_raw, const float* __restrict__ B_w,
    const float* __restrict__ C_w, const float* __restrict__ gamma,
    float* __restrict__ As, float* __restrict__ Bt, float* __restrict__ Cs,
    float* __restrict__ gs) {
    int i = blockIdx.x * 256 + threadIdx.x;   // 0 .. D*N-1
    int d = i >> 6;
    int n = i & 63;
    As[i] = sigmoidf(A_raw[i]);               // [D][N]
    Cs[i] = sigmoidf(C_w[i]);                 // [D][N]
    Bt[i] = sigmoidf(B_w[n * D_MODEL + d]);   // Bt[d][n] = sigmoid(B_w[n][d])
    if (n == 0) gs[d] = sigmoidf(gamma[d]);
}

// ---------------------------------------------------------------------------
// Kernel 1: U[row][n] = sum_d x[row][d] * Bt[d][n]   (row = b*SEQ + t)
// ---------------------------------------------------------------------------
__device__ __forceinline__ void fma4(float av, const float4 bv, float* acc) {
    acc[0] = fmaf(av, bv.x, acc[0]);
    acc[1] = fmaf(av, bv.y, acc[1]);
    acc[2] = fmaf(av, bv.z, acc[2]);
    acc[3] = fmaf(av, bv.w, acc[3]);
}

__global__ __launch_bounds__(256) void u_gemm_kernel(
    const float* __restrict__ x, const float* __restrict__ Bt,
    float* __restrict__ U) {
    __shared__ float xs[64 * 68];
    __shared__ float Bs[64 * 64];
    const int tid = threadIdx.x;
    const int row0 = blockIdx.x * 64;
    const int tr = tid >> 4;
    const int tc = tid & 15;
    float acc[4][4] = {};

    for (int d0 = 0; d0 < D_MODEL; d0 += 64) {
#pragma unroll
        for (int i = 0; i < 4; ++i) {
            int f4 = i * 1024 + tid * 4;
            int r = f4 >> 6, c = f4 & 63;
            float4 v = *(const float4*)&x[(size_t)(row0 + r) * D_MODEL + d0 + c];
            *(float4*)&xs[r * 68 + c] = v;
        }
#pragma unroll
        for (int i = 0; i < 4; ++i) {
            int f4 = i * 1024 + tid * 4;
            *(float4*)&Bs[f4] = *(const float4*)&Bt[d0 * 64 + f4];
        }
        __syncthreads();
#pragma unroll
        for (int dd = 0; dd < 64; dd += 4) {
            float4 b0 = *(const float4*)&Bs[(dd + 0) * 64 + tc * 4];
            float4 b1 = *(const float4*)&Bs[(dd + 1) * 64 + tc * 4];
            float4 b2 = *(const float4*)&Bs[(dd + 2) * 64 + tc * 4];
            float4 b3 = *(const float4*)&Bs[(dd + 3) * 64 + tc * 4];
#pragma unroll
            for (int i = 0; i < 4; ++i) {
                float4 a = *(const float4*)&xs[(tr * 4 + i) * 68 + dd];
                fma4(a.x, b0, acc[i]);
                fma4(a.y, b1, acc[i]);
                fma4(a.z, b2, acc[i]);
                fma4(a.w, b3, acc[i]);
            }
        }
        __syncthreads();
    }
#pragma unroll
    for (int i = 0; i < 4; ++i) {
        float4 v = make_float4(acc[i][0], acc[i][1], acc[i][2], acc[i][3]);
        *(float4*)&U[(size_t)(row0 + tr * 4 + i) * 64 + tc * 4] = v;
    }
}

// ---------------------------------------------------------------------------
// Kernel 2: time-split scan. Block = (b, 32-d chunk, t-chunk of 512).
// 8 lanes per d, 8 n/lane. Each t-chunk (except the first) redundantly
// recomputes WARM steps from h=0; contraction (A<=0.7311) kills the error.
// Emits UNNORMALIZED y into yraw; last chunk emits h_final.
// ---------------------------------------------------------------------------
__global__ __launch_bounds__(256, 8) void scan_kernel(
    const float* __restrict__ x, const float* __restrict__ U,
    const float* __restrict__ As, const float* __restrict__ Cs,
    float* __restrict__ yraw, float* __restrict__ hout) {
    __shared__ float Ulds[ROUND * 64];   // 8 KB
    __shared__ float xlds[ROUND * 32];   // 4 KB
    __shared__ float ylds[ROUND * 32];   // 4 KB
    const int tid = threadIdx.x;
    const int c = blockIdx.x & 7;                 // t-chunk
    const int d0 = ((blockIdx.x >> 3) & 31) * 32; // d-chunk
    const int b = blockIdx.x >> 8;                // batch
    const int g = tid >> 3;   // 0..31 -> d = d0+g
    const int l = tid & 7;    // 0..7  -> n = l*8 .. l*8+7
    const int d = d0 + g;

    float h[8], a[8], cc[8];
    {
        float4 a0 = *(const float4*)&As[d * 64 + l * 8];
        float4 a1 = *(const float4*)&As[d * 64 + l * 8 + 4];
        a[0] = a0.x; a[1] = a0.y; a[2] = a0.z; a[3] = a0.w;
        a[4] = a1.x; a[5] = a1.y; a[6] = a1.z; a[7] = a1.w;
        float4 c0 = *(const float4*)&Cs[d * 64 + l * 8];
        float4 c1 = *(const float4*)&Cs[d * 64 + l * 8 + 4];
        cc[0] = c0.x; cc[1] = c0.y; cc[2] = c0.z; cc[3] = c0.w;
        cc[4] = c1.x; cc[5] = c1.y; cc[6] = c1.z; cc[7] = c1.w;
    }
#pragma unroll
    for (int j = 0; j < 8; ++j) h[j] = 0.0f;

    const size_t xbase = (size_t)b * SEQ * D_MODEL;
    const size_t ubase = (size_t)b * SEQ * 64;
    const int t_main = c * T_CHUNK;
    const int t_begin = (c == 0) ? 0 : t_main - WARM;
    const int t_end = t_main + T_CHUNK;

    for (int t0 = t_begin; t0 < t_end; t0 += ROUND) {
        // stage U round: ROUND steps x 64 n (contiguous)
#pragma unroll
        for (int i = 0; i < 2; ++i) {
            int f4 = i * 1024 + tid * 4;
            *(float4*)&Ulds[f4] =
                *(const float4*)&U[ubase + (size_t)t0 * 64 + f4];
        }
        // stage x round: ROUND steps x 32 d
        {
            int f4 = tid * 4;
            int tt = f4 >> 5, dd = f4 & 31;
            *(float4*)&xlds[f4] =
                *(const float4*)&x[xbase + (size_t)(t0 + tt) * D_MODEL + d0 + dd];
        }
        __syncthreads();

        const bool emit = (t0 >= t_main);
        if (emit) {
#pragma unroll 4
            for (int tt = 0; tt < ROUND; ++tt) {
                float4 u0 = *(const float4*)&Ulds[tt * 64 + l * 8];
                float4 u1 = *(const float4*)&Ulds[tt * 64 + l * 8 + 4];
                float xt = xlds[tt * 32 + g];
                float uu[8] = {u0.x, u0.y, u0.z, u0.w, u1.x, u1.y, u1.z, u1.w};
                float y0 = 0.0f, y1 = 0.0f;
#pragma unroll
                for (int j = 0; j < 4; ++j) {
                    h[j] = __builtin_amdgcn_fmed3f(
                        fmaf(h[j], a[j], uu[j] * xt), 0.0f, 1.0f);
                    y0 = fmaf(h[j], cc[j], y0);
                }
#pragma unroll
                for (int j = 4; j < 8; ++j) {
                    h[j] = __builtin_amdgcn_fmed3f(
                        fmaf(h[j], a[j], uu[j] * xt), 0.0f, 1.0f);
                    y1 = fmaf(h[j], cc[j], y1);
                }
                float y = y0 + y1;
                y += __shfl_xor(y, 1);
                y += __shfl_xor(y, 2);
                y += __shfl_xor(y, 4);
                if (l == 0) ylds[tt * 32 + g] = y;
            }
        } else {
            // warm-up: advance h only, no y
#pragma unroll 4
            for (int tt = 0; tt < ROUND; ++tt) {
                float4 u0 = *(const float4*)&Ulds[tt * 64 + l * 8];
                float4 u1 = *(const float4*)&Ulds[tt * 64 + l * 8 + 4];
                float xt = xlds[tt * 32 + g];
                float uu[8] = {u0.x, u0.y, u0.z, u0.w, u1.x, u1.y, u1.z, u1.w};
#pragma unroll
                for (int j = 0; j < 8; ++j) {
                    h[j] = __builtin_amdgcn_fmed3f(
                        fmaf(h[j], a[j], uu[j] * xt), 0.0f, 1.0f);
                }
            }
        }
        __syncthreads();

        if (emit) {
            int f4 = tid * 4;
            int tt = f4 >> 5, dd = f4 & 31;
            *(float4*)&yraw[xbase + (size_t)(t0 + tt) * D_MODEL + d0 + dd] =
                *(const float4*)&ylds[f4];
        }
        // Ulds/xlds rewrite next round is fenced by the post-stage sync;
        // ylds flush-read vs next compute-write is fenced the same way.
    }

    if (c == (SEQ / T_CHUNK) - 1) {
        float4 h0 = make_float4(h[0], h[1], h[2], h[3]);
        float4 h1 = make_float4(h[4], h[5], h[6], h[7]);
        size_t hoff = ((size_t)b * D_MODEL + d) * 64 + l * 8;
        *(float4*)&hout[hoff] = h0;
        *(float4*)&hout[hoff + 4] = h1;
    }
}

// ---------------------------------------------------------------------------
// Kernel 3: in-place normalize: out = clip(g*y/(sum_d y + eps) + x, 0, 1)
// ---------------------------------------------------------------------------
__global__ __launch_bounds__(256) void norm_kernel(
    const float* __restrict__ x, const float* __restrict__ gs,
    float* __restrict__ y) {
    __shared__ float red[4];
    const int tid = threadIdx.x;
    const size_t base = (size_t)blockIdx.x * D_MODEL;

    float4 yv = *(const float4*)&y[base + tid * 4];
    float s = yv.x + yv.y + yv.z + yv.w;
#pragma unroll
    for (int off = 1; off < 64; off <<= 1) s += __shfl_xor(s, off);
    if ((tid & 63) == 0) red[tid >> 6] = s;
    __syncthreads();
    float tot = red[0] + red[1] + red[2] + red[3];
    float inv = 1.0f / (tot + EPS);

    float4 xv = *(const float4*)&x[base + tid * 4];
    float4 gv = *(const float4*)&gs[tid * 4];
    float4 o;
    o.x = __builtin_amdgcn_fmed3f(fmaf(gv.x * yv.x, inv, xv.x), 0.0f, 1.0f);
    o.y = __builtin_amdgcn_fmed3f(fmaf(gv.y * yv.y, inv, xv.y), 0.0f, 1.0f);
    o.z = __builtin_amdgcn_fmed3f(fmaf(gv.z * yv.z, inv, xv.z), 0.0f, 1.0f);
    o.w = __builtin_amdgcn_fmed3f(fmaf(gv.w * yv.w, inv, xv.w), 0.0f, 1.0f);
    *(float4*)&y[base + tid * 4] = o;
}

// ---------------------------------------------------------------------------
extern "C" void kernel_launch(void* const* d_in, const int* in_sizes, int n_in,
                              void* d_out, int out_size, void* d_ws,
                              size_t ws_size, hipStream_t stream) {
    const float* x     = (const float*)d_in[0];
    const float* A_raw = (const float*)d_in[1];
    const float* B_w   = (const float*)d_in[2];
    const float* C_w   = (const float*)d_in[3];
    const float* gamma = (const float*)d_in[4];

    float* out  = (float*)d_out;
    float* yout = out;                                      // [B,S,D]
    float* hout = out + (size_t)B_BATCH * SEQ * D_MODEL;    // [B,D,N]

    float* ws = (float*)d_ws;
    float* As = ws;                  // 65536
    float* Bt = ws + 65536;          // 65536
    float* Cs = ws + 131072;         // 65536
    float* gs = ws + 196608;         // 1024
    float* U  = ws + 197632;         // B*SEQ*64 = 2097152

    prep_kernel<<<256, 256, 0, stream>>>(A_raw, B_w, C_w, gamma, As, Bt, Cs, gs);
    u_gemm_kernel<<<(B_BATCH * SEQ) / 64, 256, 0, stream>>>(x, Bt, U);
    scan_kernel<<<B_BATCH * (D_MODEL / 32) * (SEQ / T_CHUNK), 256, 0, stream>>>(
        x, U, As, Cs, yout, hout);
    norm_kernel<<<B_BATCH * SEQ, 256, 0, stream>>>(x, gs, yout);
}